// Round 1
// baseline (107.183 us; speedup 1.0000x reference)
//
#include <hip/hip_runtime.h>
#include <math.h>

// Problem: B=16, N=16384, M=256 (derived from in_sizes at runtime).
// Outputs: gt_offset (B,3,N) f32 then total scalar, concatenated in d_out.
//
// Workspace layout (bytes):
//   [0,            B*M*4)            counts   (float)
//   [cntB,         cntB + B*M*12)    sums     (float, [b*M+m][3])
//   [sumE,         sumE + B*M*4)     gvar     (float)
//   [gvarE,        gvarE + 4)        sl1_sum  (float)
//   [IND_OFF, ...)                   ind      (int, B*N)
// Zero region = everything before IND_OFF (memset each call; ws is re-poisoned).

#define BLK 256

__global__ __launch_bounds__(BLK) void k1_nearest(
    const float* __restrict__ data,       // (B,3,N)
    const float* __restrict__ cpts,       // (B,M,3)
    const float* __restrict__ pred,       // (B,3,N)
    const int*   __restrict__ tc_arr,     // (B,)
    const int*   __restrict__ label_arr,  // (B,)
    float* __restrict__ gt_out,           // (B,3,N)
    float* __restrict__ counts,           // (B,M)
    float* __restrict__ sums,             // (B,M,3)
    float* __restrict__ sl1_sum,          // (1,)
    int*   __restrict__ ind,              // (B,N)
    int N, int M, int blocksPerB)
{
    __shared__ float4 c4[256];                 // x,y,z,|c|^2
    __shared__ float lcnt[256], lsx[256], lsy[256], lsz[256];
    __shared__ float red[BLK / 64];

    const int b     = blockIdx.x / blocksPerB;
    const int chunk = blockIdx.x % blocksPerB;
    const int t     = threadIdx.x;
    const int n     = chunk * BLK + t;

    const int tc  = tc_arr[b];
    const int lab = label_arr[b];

    if (t < M) {
        float x = cpts[((size_t)b * M + t) * 3 + 0];
        float y = cpts[((size_t)b * M + t) * 3 + 1];
        float z = cpts[((size_t)b * M + t) * 3 + 2];
        c4[t] = make_float4(x, y, z, x * x + y * y + z * z);
    }
    lcnt[t] = 0.f; lsx[t] = 0.f; lsy[t] = 0.f; lsz[t] = 0.f;
    __syncthreads();

    const size_t base = (size_t)b * 3 * N + n;
    const float px = data[base], py = data[base + N], pz = data[base + 2 * (size_t)N];
    const float qx = pred[base], qy = pred[base + N], qz = pred[base + 2 * (size_t)N];
    const float pp = px * px + py * py + pz * pz;

    int   bi   = 0;
    float best = INFINITY;
    for (int m = 0; m < tc; ++m) {
        float4 c = c4[m];
        float dot = fmaf(c.x, px, fmaf(c.y, py, c.z * pz));
        float d2  = fmaf(-2.f, dot, pp + c.w);
        if (d2 < best) { best = d2; bi = m; }
    }

    float gx = 0.f, gy = 0.f, gz = 0.f;
    if (tc > 0) {
        float4 c = c4[bi];
        gx = c.x - px; gy = c.y - py; gz = c.z - pz;
    }
    gt_out[base]                 = gx;
    gt_out[base + N]             = gy;
    gt_out[base + 2 * (size_t)N] = gz;
    ind[(size_t)b * N + n] = bi;

    // cluster accumulation (only batches with contacts contribute to variance)
    if (tc > 0) {
        float ex = px + qx, ey = py + qy, ez = pz + qz;
        atomicAdd(&lcnt[bi], 1.f);
        atomicAdd(&lsx[bi], ex);
        atomicAdd(&lsy[bi], ey);
        atomicAdd(&lsz[bi], ez);
    }

    // smooth-L1 (masked by contact_label==1; includes tc==0 batches with gt=0)
    float s = 0.f;
    if (lab == 1) {
        float d, a;
        d = gx - qx; a = fabsf(d); s += (a < 1.f) ? 0.5f * d * d : (a - 0.5f);
        d = gy - qy; a = fabsf(d); s += (a < 1.f) ? 0.5f * d * d : (a - 0.5f);
        d = gz - qz; a = fabsf(d); s += (a < 1.f) ? 0.5f * d * d : (a - 0.5f);
    }
    #pragma unroll
    for (int o = 32; o > 0; o >>= 1) s += __shfl_down(s, o, 64);
    if ((t & 63) == 0) red[t >> 6] = s;
    __syncthreads();   // also orders the LDS cluster atomics above

    if (t == 0) {
        float tot = 0.f;
        #pragma unroll
        for (int w = 0; w < BLK / 64; ++w) tot += red[w];
        atomicAdd(sl1_sum, tot);
    }
    if (t < M && lcnt[t] > 0.f) {
        atomicAdd(&counts[(size_t)b * M + t], lcnt[t]);
        atomicAdd(&sums[((size_t)b * M + t) * 3 + 0], lsx[t]);
        atomicAdd(&sums[((size_t)b * M + t) * 3 + 1], lsy[t]);
        atomicAdd(&sums[((size_t)b * M + t) * 3 + 2], lsz[t]);
    }
}

__global__ __launch_bounds__(BLK) void k2_var(
    const float* __restrict__ data,
    const float* __restrict__ pred,
    const int*   __restrict__ tc_arr,
    const float* __restrict__ counts,
    const float* __restrict__ sums,
    const int*   __restrict__ ind,
    float* __restrict__ gvar,
    int N, int M, int blocksPerB)
{
    __shared__ float lv[256];
    const int b     = blockIdx.x / blocksPerB;
    const int chunk = blockIdx.x % blocksPerB;
    const int t     = threadIdx.x;
    const int n     = chunk * BLK + t;
    const int tc    = tc_arr[b];

    lv[t] = 0.f;
    __syncthreads();

    if (tc > 0) {
        const size_t base = (size_t)b * 3 * N + n;
        float ex = data[base]                 + pred[base];
        float ey = data[base + N]             + pred[base + N];
        float ez = data[base + 2 * (size_t)N] + pred[base + 2 * (size_t)N];
        int bi = ind[(size_t)b * N + n];
        size_t ci = (size_t)b * M + bi;
        float c   = counts[ci];
        float den = fmaxf(c, 1.f);
        float mx = sums[ci * 3 + 0] / den;
        float my = sums[ci * 3 + 1] / den;
        float mz = sums[ci * 3 + 2] / den;
        float dx = ex - mx, dy = ey - my, dz = ez - mz;
        atomicAdd(&lv[bi], dx * dx + dy * dy + dz * dz);
    }
    __syncthreads();
    if (t < M && lv[t] != 0.f) atomicAdd(&gvar[(size_t)b * M + t], lv[t]);
}

__global__ __launch_bounds__(BLK) void k3_final(
    const int*   __restrict__ tc_arr,
    const int*   __restrict__ label_arr,
    const float* __restrict__ counts,
    const float* __restrict__ gvar,
    const float* __restrict__ sl1_sum,
    float* __restrict__ out_total,
    int B, int M, int N)
{
    __shared__ float red[BLK];
    const int t = threadIdx.x;
    float acc = 0.f;
    for (int i = t; i < B * M; i += BLK) {
        int b = i / M;
        if (tc_arr[b] > 0) {
            float c = counts[i];
            if (c > 0.f) acc += gvar[i] / c;   // max(c,1)==c here
        }
    }
    red[t] = acc;
    __syncthreads();
    #pragma unroll
    for (int o = BLK / 2; o > 0; o >>= 1) {
        if (t < o) red[t] += red[t + o];
        __syncthreads();
    }
    if (t == 0) {
        int nvalid = 0, nlab = 0;
        for (int b = 0; b < B; ++b) {
            nvalid += (tc_arr[b] > 0);
            nlab   += (label_arr[b] == 1);
        }
        float var_loss = red[0] / ((float)nvalid + 1e-16f);
        float n_sel    = (float)nlab * 3.f * (float)N;
        float off_loss = (n_sel > 0.f) ? (sl1_sum[0] / n_sel) : 0.f;
        out_total[0] = off_loss * 10.f + var_loss * 2.f;
    }
}

extern "C" void kernel_launch(void* const* d_in, const int* in_sizes, int n_in,
                              void* d_out, int out_size, void* d_ws, size_t ws_size,
                              hipStream_t stream) {
    const float* data  = (const float*)d_in[0];
    const float* cpts  = (const float*)d_in[1];
    const float* pred  = (const float*)d_in[2];
    const int*   tc    = (const int*)d_in[3];
    const int*   label = (const int*)d_in[4];

    const int B = in_sizes[3];
    const int N = in_sizes[0] / (3 * B);
    const int M = in_sizes[1] / (3 * B);

    float* gt_out    = (float*)d_out;
    float* out_total = gt_out + (size_t)B * 3 * N;

    char*  ws      = (char*)d_ws;
    float* counts  = (float*)ws;                               // B*M
    float* sums    = counts + (size_t)B * M;                   // B*M*3
    float* gvar    = sums + (size_t)B * M * 3;                 // B*M
    float* sl1     = gvar + (size_t)B * M;                     // 1
    size_t zeroBytes = ((size_t)B * M * 5 + 1) * sizeof(float);
    size_t indOff  = (zeroBytes + 255) & ~(size_t)255;
    int*   ind     = (int*)(ws + indOff);                      // B*N

    hipMemsetAsync(d_ws, 0, zeroBytes, stream);

    const int blocksPerB = N / BLK;
    dim3 grid(B * blocksPerB), blk(BLK);
    k1_nearest<<<grid, blk, 0, stream>>>(data, cpts, pred, tc, label,
                                         gt_out, counts, sums, sl1, ind,
                                         N, M, blocksPerB);
    k2_var<<<grid, blk, 0, stream>>>(data, pred, tc, counts, sums, ind, gvar,
                                     N, M, blocksPerB);
    k3_final<<<1, blk, 0, stream>>>(tc, label, counts, gvar, sl1, out_total,
                                    B, M, N);
}

// Round 3
// 106.471 us; speedup vs baseline: 1.0067x; 1.0067x over previous
//
#include <hip/hip_runtime.h>
#include <math.h>

// B=16, N=16384, M=256 (derived at runtime).
// d_out: gt_offset (B,3,N) f32 followed by scalar total.
//
// One fused pass (k1): nearest-contact argmin + gt_offset write + smooth-L1
// partial + per-cluster {count, sum(e), sum(|e|^2)} accumulation.
// Variance uses the identity  sum||e-mu||^2 = sum||e||^2 - ||sum e||^2/count,
// so no second pass over points is needed.
//
// Workspace (floats): counts[B*M] | sums[B*M*3] | sq[B*M] | sl1[1]
// All zeroed by one small memset (5*B*M+1 floats ~ 82 KB).

#define BLK 256
#define VPT 2   // points per thread

__global__ __launch_bounds__(BLK) void k1_fused(
    const float* __restrict__ data,       // (B,3,N)
    const float* __restrict__ cpts,       // (B,M,3)
    const float* __restrict__ pred,       // (B,3,N)
    const int*   __restrict__ tc_arr,     // (B,)
    const int*   __restrict__ label_arr,  // (B,)
    float* __restrict__ gt_out,           // (B,3,N)
    float* __restrict__ counts,           // (B,M)
    float* __restrict__ sums,             // (B,M,3)
    float* __restrict__ sqsum,            // (B,M)
    float* __restrict__ sl1_sum,          // (1,)
    int N, int M, int blocksPerB)
{
    __shared__ float4 c4[256];                                  // x,y,z,|c|^2
    __shared__ float lcnt[256], lsx[256], lsy[256], lsz[256], lsq[256];
    __shared__ float red[BLK / 64];

    const int b     = blockIdx.x / blocksPerB;
    const int chunk = blockIdx.x % blocksPerB;
    const int t     = threadIdx.x;
    const int tc    = tc_arr[b];
    const int lab   = label_arr[b];

    if (t < M) {
        float x = cpts[((size_t)b * M + t) * 3 + 0];
        float y = cpts[((size_t)b * M + t) * 3 + 1];
        float z = cpts[((size_t)b * M + t) * 3 + 2];
        c4[t] = make_float4(x, y, z, x * x + y * y + z * z);
        lcnt[t] = 0.f; lsx[t] = 0.f; lsy[t] = 0.f; lsz[t] = 0.f; lsq[t] = 0.f;
    }
    __syncthreads();

    const int n0 = chunk * (BLK * VPT) + t;      // + v*BLK, coalesced
    const size_t base = (size_t)b * 3 * N;

    float px[VPT], py[VPT], pz[VPT], qx[VPT], qy[VPT], qz[VPT], ppw[VPT];
    #pragma unroll
    for (int v = 0; v < VPT; ++v) {
        const size_t i = base + n0 + v * BLK;
        px[v] = data[i]; py[v] = data[i + N]; pz[v] = data[i + 2 * (size_t)N];
        qx[v] = pred[i]; qy[v] = pred[i + N]; qz[v] = pred[i + 2 * (size_t)N];
        ppw[v] = px[v] * px[v] + py[v] * py[v] + pz[v] * pz[v];
    }

    float best[VPT]; int bi[VPT];
    #pragma unroll
    for (int v = 0; v < VPT; ++v) { best[v] = INFINITY; bi[v] = 0; }

    for (int m = 0; m < tc; ++m) {
        float4 c = c4[m];
        #pragma unroll
        for (int v = 0; v < VPT; ++v) {
            float dot = fmaf(c.x, px[v], fmaf(c.y, py[v], c.z * pz[v]));
            float d2  = fmaf(-2.f, dot, ppw[v] + c.w);
            bool lt = d2 < best[v];
            best[v] = lt ? d2 : best[v];
            bi[v]   = lt ? m  : bi[v];
        }
    }

    float s = 0.f;
    #pragma unroll
    for (int v = 0; v < VPT; ++v) {
        float gx = 0.f, gy = 0.f, gz = 0.f;
        if (tc > 0) {
            float4 c = c4[bi[v]];
            gx = c.x - px[v]; gy = c.y - py[v]; gz = c.z - pz[v];
        }
        const size_t i = base + n0 + v * BLK;
        gt_out[i]                 = gx;
        gt_out[i + N]             = gy;
        gt_out[i + 2 * (size_t)N] = gz;

        if (tc > 0) {
            float ex = px[v] + qx[v], ey = py[v] + qy[v], ez = pz[v] + qz[v];
            atomicAdd(&lcnt[bi[v]], 1.f);
            atomicAdd(&lsx[bi[v]], ex);
            atomicAdd(&lsy[bi[v]], ey);
            atomicAdd(&lsz[bi[v]], ez);
            atomicAdd(&lsq[bi[v]], ex * ex + ey * ey + ez * ez);
        }
        if (lab == 1) {
            float d, a;
            d = gx - qx[v]; a = fabsf(d); s += (a < 1.f) ? 0.5f * d * d : (a - 0.5f);
            d = gy - qy[v]; a = fabsf(d); s += (a < 1.f) ? 0.5f * d * d : (a - 0.5f);
            d = gz - qz[v]; a = fabsf(d); s += (a < 1.f) ? 0.5f * d * d : (a - 0.5f);
        }
    }

    #pragma unroll
    for (int o = 32; o > 0; o >>= 1) s += __shfl_down(s, o, 64);
    if ((t & 63) == 0) red[t >> 6] = s;
    __syncthreads();   // also orders LDS cluster atomics

    if (t == 0) {
        float tot = 0.f;
        #pragma unroll
        for (int w = 0; w < BLK / 64; ++w) tot += red[w];
        atomicAdd(sl1_sum, tot);
    }
    if (t < M && lcnt[t] > 0.f) {
        const size_t ci = (size_t)b * M + t;
        atomicAdd(&counts[ci], lcnt[t]);
        atomicAdd(&sums[ci * 3 + 0], lsx[t]);
        atomicAdd(&sums[ci * 3 + 1], lsy[t]);
        atomicAdd(&sums[ci * 3 + 2], lsz[t]);
        atomicAdd(&sqsum[ci], lsq[t]);
    }
}

__global__ __launch_bounds__(BLK) void k3_final(
    const int*   __restrict__ tc_arr,
    const int*   __restrict__ label_arr,
    const float* __restrict__ counts,
    const float* __restrict__ sums,
    const float* __restrict__ sqsum,
    const float* __restrict__ sl1_sum,
    float* __restrict__ out_total,
    int B, int M, int N)
{
    __shared__ float red[BLK];
    const int t = threadIdx.x;
    float acc = 0.f;
    for (int i = t; i < B * M; i += BLK) {
        int b = i / M;
        if (tc_arr[b] > 0) {
            float c = counts[i];
            if (c > 0.f) {
                float sx = sums[(size_t)i * 3 + 0];
                float sy = sums[(size_t)i * 3 + 1];
                float sz = sums[(size_t)i * 3 + 2];
                float var = sqsum[i] - (sx * sx + sy * sy + sz * sz) / c;
                acc += var / c;
            }
        }
    }
    red[t] = acc;
    __syncthreads();
    #pragma unroll
    for (int o = BLK / 2; o > 0; o >>= 1) {
        if (t < o) red[t] += red[t + o];
        __syncthreads();
    }
    if (t == 0) {
        int nvalid = 0, nlab = 0;
        for (int b = 0; b < B; ++b) {
            nvalid += (tc_arr[b] > 0);
            nlab   += (label_arr[b] == 1);
        }
        float var_loss = red[0] / ((float)nvalid + 1e-16f);
        float n_sel    = (float)nlab * 3.f * (float)N;
        float off_loss = (n_sel > 0.f) ? (sl1_sum[0] / n_sel) : 0.f;
        out_total[0] = off_loss * 10.f + var_loss * 2.f;
    }
}

extern "C" void kernel_launch(void* const* d_in, const int* in_sizes, int n_in,
                              void* d_out, int out_size, void* d_ws, size_t ws_size,
                              hipStream_t stream) {
    const float* data  = (const float*)d_in[0];
    const float* cpts  = (const float*)d_in[1];
    const float* pred  = (const float*)d_in[2];
    const int*   tc    = (const int*)d_in[3];
    const int*   label = (const int*)d_in[4];

    const int B = in_sizes[3];
    const int N = in_sizes[0] / (3 * B);
    const int M = in_sizes[1] / (3 * B);

    float* gt_out    = (float*)d_out;
    float* out_total = gt_out + (size_t)B * 3 * N;

    float* counts = (float*)d_ws;                 // B*M
    float* sums   = counts + (size_t)B * M;       // B*M*3
    float* sq     = sums + (size_t)B * M * 3;     // B*M
    float* sl1    = sq + (size_t)B * M;           // 1
    size_t zeroBytes = ((size_t)B * M * 5 + 1) * sizeof(float);

    hipMemsetAsync(d_ws, 0, zeroBytes, stream);

    const int blocksPerB = N / (BLK * VPT);
    k1_fused<<<dim3(B * blocksPerB), dim3(BLK), 0, stream>>>(
        data, cpts, pred, tc, label, gt_out, counts, sums, sq, sl1,
        N, M, blocksPerB);
    k3_final<<<dim3(1), dim3(BLK), 0, stream>>>(
        tc, label, counts, sums, sq, sl1, out_total, B, M, N);
}